// Round 5
// baseline (420.743 us; speedup 1.0000x reference)
//
#include <hip/hip_runtime.h>
#include <hip/hip_bf16.h>
#include <cstdint>

#define N_HEAD 16
#define HEAD_DIM 128

typedef __bf16 bf16;
typedef __bf16 bf16x8 __attribute__((ext_vector_type(8)));
typedef __bf16 bf16x4 __attribute__((ext_vector_type(4)));
typedef float f32x4 __attribute__((ext_vector_type(4)));

// async global->LDS 16B (per-lane lds addr must be base + lane*16)
__device__ __forceinline__ void gload_lds16(const void* g, void* l) {
  auto gp = reinterpret_cast<const __attribute__((address_space(1))) char*>(
      reinterpret_cast<uintptr_t>(g));
  auto lp = reinterpret_cast<__attribute__((address_space(3))) char*>(
      reinterpret_cast<uintptr_t>(l));
  __builtin_amdgcn_global_load_lds(gp, lp, 16, 0, 0);
}

// ------- fp32 -> bf16 convert, all 5 tensors in one launch (z selects) ------
__global__ __launch_bounds__(256) void cvt_all(
    const float* __restrict__ x, const float* __restrict__ Wq,
    const float* __restrict__ Wk, const float* __restrict__ Wv,
    const float* __restrict__ Wp, bf16* __restrict__ xb,
    bf16* __restrict__ wqkv, bf16* __restrict__ wpb, int nx4, int nw4) {
  const int z = blockIdx.z;
  const float* in;
  bf16* out;
  int n4;
  if (z == 0)      { in = x;  out = xb;  n4 = nx4; }
  else if (z == 1) { in = Wq; out = wqkv;                     n4 = nw4; }
  else if (z == 2) { in = Wk; out = wqkv + (size_t)nw4 * 4;   n4 = nw4; }
  else if (z == 3) { in = Wv; out = wqkv + (size_t)nw4 * 8;   n4 = nw4; }
  else             { in = Wp; out = wpb;  n4 = nw4; }
  const int i = blockIdx.x * 256 + threadIdx.x;
  if (i >= n4) return;
  const float4 f = reinterpret_cast<const float4*>(in)[i];
  bf16x4 o;
  o.x = (bf16)f.x; o.y = (bf16)f.y; o.z = (bf16)f.z; o.w = (bf16)f.w;
  reinterpret_cast<bf16x4*>(out)[i] = o;
}

// ---------------- 256x256 8-phase GEMM (bf16 in/out) ------------------------
// BM=BN=256, BK=64, 512 threads (8 waves = 2Mx4N), per-wave C = 128x64.
// Verified round 2: bank-conflict 0. Grid = (M/256)*NT blocks, NT columns.
__global__ __launch_bounds__(512, 2) void gemm256(
    const bf16* __restrict__ A, const bf16* __restrict__ Bt,
    bf16* __restrict__ C, int M, int N, int K) {
  __shared__ __align__(16) char sA[2][32768];
  __shared__ __align__(16) char sB[2][32768];

  const int nwgy = M >> 8;
  const int nwg = gridDim.x;
  const int q8 = nwg >> 3;
  const int wgid = (blockIdx.x & 7) * q8 + (blockIdx.x >> 3);
  const int by = wgid % nwgy;
  const int bx = wgid / nwgy;

  const int tid = threadIdx.x;
  const int lane = tid & 63;
  const int wave = tid >> 6;
  const int wm = (wave >> 2) << 7;   // 0 / 128
  const int wn = (wave & 3) << 6;    // 0..192
  const int lr = lane & 15;
  const int lk16 = (lane >> 4) << 4; // quad's 16B k-group
  const int sx = (lr & 7) << 4;      // read-side swizzle XOR (row&7)<<4

  const bf16* Ab = A + (size_t)by * 256 * K;
  const bf16* Bb = Bt + (size_t)bx * 256 * K;

  int srow[2], scol[2];
#pragma unroll
  for (int pp = 0; pp < 2; ++pp) {
    const int o = pp * 8192 + tid * 16;
    srow[pp] = o >> 7;
    scol[pp] = (o & 127) ^ ((srow[pp] & 7) << 4);
  }

  auto stageA = [&](int buf, int half, int k0) {
#pragma unroll
    for (int pp = 0; pp < 2; ++pp)
      gload_lds16(Ab + (size_t)(half * 128 + srow[pp]) * K + k0 + (scol[pp] >> 1),
                  sA[buf] + half * 16384 + pp * 8192 + tid * 16);
  };
  auto stageB = [&](int buf, int half, int k0) {
#pragma unroll
    for (int pp = 0; pp < 2; ++pp)
      gload_lds16(Bb + (size_t)(half * 128 + srow[pp]) * K + k0 + (scol[pp] >> 1),
                  sB[buf] + half * 16384 + pp * 8192 + tid * 16);
  };

  f32x4 acc[8][4] = {};
  bf16x8 bF[4][2];

#define VMCNT4                                             \
  asm volatile("s_waitcnt vmcnt(4)" ::: "memory");         \
  __builtin_amdgcn_sched_barrier(0)
#define VMCNT0                                             \
  asm volatile("s_waitcnt vmcnt(0)" ::: "memory");         \
  __builtin_amdgcn_sched_barrier(0)

#define PHASE(BUF, P, STAGE, WAIT)                                             \
  {                                                                            \
    bf16x8 aF[2][2];                                                           \
    if (P == 0) {                                                              \
      _Pragma("unroll") for (int n = 0; n < 4; ++n)                            \
      _Pragma("unroll") for (int ks = 0; ks < 2; ++ks)                         \
        bF[n][ks] = *reinterpret_cast<const bf16x8*>(                          \
            sB[BUF] + (wn + n * 16 + lr) * 128 + ((ks * 64 + lk16) ^ sx));     \
    }                                                                          \
    _Pragma("unroll") for (int mi = 0; mi < 2; ++mi)                           \
    _Pragma("unroll") for (int ks = 0; ks < 2; ++ks)                           \
      aF[mi][ks] = *reinterpret_cast<const bf16x8*>(                           \
          sA[BUF] + (wm + (P * 2 + mi) * 16 + lr) * 128 +                      \
          ((ks * 64 + lk16) ^ sx));                                            \
    STAGE;                                                                     \
    WAIT;                                                                      \
    __builtin_amdgcn_s_barrier();                                              \
    __builtin_amdgcn_s_setprio(1);                                             \
    _Pragma("unroll") for (int ks = 0; ks < 2; ++ks)                           \
    _Pragma("unroll") for (int mi = 0; mi < 2; ++mi)                           \
    _Pragma("unroll") for (int n = 0; n < 4; ++n)                              \
      acc[P * 2 + mi][n] = __builtin_amdgcn_mfma_f32_16x16x32_bf16(            \
          aF[mi][ks], bF[n][ks], acc[P * 2 + mi][n], 0, 0, 0);                 \
    __builtin_amdgcn_s_setprio(0);                                             \
    __builtin_amdgcn_s_barrier();                                              \
  }

  const int nIt = K >> 7;  // 2 K-steps (BK=64) per iteration

  stageB(0, 0, 0); stageB(0, 1, 0);
  stageA(0, 0, 0); stageA(0, 1, 0);
  stageB(1, 0, 64); stageB(1, 1, 64);
  VMCNT4;
  __builtin_amdgcn_s_barrier();

  int k0 = 0;
  for (int it = 0; it < nIt - 1; ++it, k0 += 128) {
    PHASE(0, 0, stageA(1, 0, k0 + 64), );
    PHASE(0, 1, stageA(1, 1, k0 + 64), );
    PHASE(0, 2, stageB(0, 0, k0 + 128), );
    PHASE(0, 3, stageB(0, 1, k0 + 128), VMCNT4);
    PHASE(1, 0, stageA(0, 0, k0 + 128), );
    PHASE(1, 1, stageA(0, 1, k0 + 128), );
    PHASE(1, 2, stageB(1, 0, k0 + 192), );
    PHASE(1, 3, stageB(1, 1, k0 + 192), VMCNT4);
  }
  PHASE(0, 0, stageA(1, 0, k0 + 64), );
  PHASE(0, 1, stageA(1, 1, k0 + 64), );
  PHASE(0, 2, , );
  PHASE(0, 3, , VMCNT0);
  PHASE(1, 0, , );
  PHASE(1, 1, , );
  PHASE(1, 2, , );
  PHASE(1, 3, , );
#undef PHASE
#undef VMCNT4
#undef VMCNT0

  const int orow = by * 256 + wm + (lane >> 4) * 4;
  const int ocol = bx * 256 + wn + lr;
#pragma unroll
  for (int m = 0; m < 8; ++m)
#pragma unroll
    for (int n = 0; n < 4; ++n)
#pragma unroll
      for (int r = 0; r < 4; ++r)
        C[(size_t)(orow + m * 16 + r) * N + (ocol + n * 16)] = (bf16)acc[m][n][r];
}

// ---------------- 128x256 8-phase GEMM (templated OutT) ---------------------
// BM=128, BN=256, BK=64, 512 threads (8 waves, 1Mx8N: per-wave C = 128x32).
// LDS 96 KiB. Deep stage/wait ledger (verified round 3).
template <typename OutT>
__global__ __launch_bounds__(512, 2) void gemm128(
    const bf16* __restrict__ A, const bf16* __restrict__ Bt,
    OutT* __restrict__ C, int M, int Ncols, int K, int nOff) {
  __shared__ __align__(16) char sA[2][16384];
  __shared__ __align__(16) char sB[2][32768];

  const int nwgy = M >> 7;
  const int nwg = gridDim.x;
  const int q8 = nwg >> 3;
  const int wgid = (blockIdx.x & 7) * q8 + (blockIdx.x >> 3);
  const int by = wgid % nwgy;
  const int bx = wgid / nwgy;

  const int tid = threadIdx.x;
  const int lane = tid & 63;
  const int wave = tid >> 6;
  const int wn = wave << 5;          // 0..224
  const int lr = lane & 15;
  const int lk16 = (lane >> 4) << 4;
  const int sx = (lr & 7) << 4;

  const bf16* Ab = A + (size_t)by * 128 * K;
  const bf16* Bb = Bt + (size_t)(nOff + bx * 256) * K;

  int srow[2], scol[2];
#pragma unroll
  for (int pp = 0; pp < 2; ++pp) {
    const int o = pp * 8192 + tid * 16;
    srow[pp] = o >> 7;
    scol[pp] = (o & 127) ^ ((srow[pp] & 7) << 4);
  }

  auto stageB = [&](int buf, int half, int k0) {
#pragma unroll
    for (int pp = 0; pp < 2; ++pp)
      gload_lds16(Bb + (size_t)(half * 128 + srow[pp]) * K + k0 + (scol[pp] >> 1),
                  sB[buf] + half * 16384 + pp * 8192 + tid * 16);
  };
  auto stageA = [&](int buf, int half, int k0) {
    const int o = tid * 16;
    const int row = o >> 7;  // 0..63
    const int col = (o & 127) ^ ((row & 7) << 4);
    gload_lds16(Ab + (size_t)(half * 64 + row) * K + k0 + (col >> 1),
                sA[buf] + half * 8192 + o);
  };

  f32x4 acc[8][2] = {};
  bf16x8 bF[2][2];

#define WAITV(n)                                               \
  asm volatile("s_waitcnt vmcnt(" #n ")" ::: "memory");        \
  __builtin_amdgcn_sched_barrier(0)

#define PH128(BUF, P, STAGE, WAIT)                                             \
  {                                                                            \
    bf16x8 aF[2][2];                                                           \
    if (P == 0) {                                                              \
      _Pragma("unroll") for (int n = 0; n < 2; ++n)                            \
      _Pragma("unroll") for (int ks = 0; ks < 2; ++ks)                         \
        bF[n][ks] = *reinterpret_cast<const bf16x8*>(                          \
            sB[BUF] + (wn + n * 16 + lr) * 128 + ((ks * 64 + lk16) ^ sx));     \
    }                                                                          \
    _Pragma("unroll") for (int mi = 0; mi < 2; ++mi)                           \
    _Pragma("unroll") for (int ks = 0; ks < 2; ++ks)                           \
      aF[mi][ks] = *reinterpret_cast<const bf16x8*>(                           \
          sA[BUF] + ((P * 2 + mi) * 16 + lr) * 128 + ((ks * 64 + lk16) ^ sx)); \
    STAGE;                                                                     \
    WAIT;                                                                      \
    __builtin_amdgcn_s_barrier();                                              \
    __builtin_amdgcn_s_setprio(1);                                             \
    _Pragma("unroll") for (int ks = 0; ks < 2; ++ks)                           \
    _Pragma("unroll") for (int mi = 0; mi < 2; ++mi)                           \
    _Pragma("unroll") for (int n = 0; n < 2; ++n)                              \
      acc[P * 2 + mi][n] = __builtin_amdgcn_mfma_f32_16x16x32_bf16(            \
          aF[mi][ks], bF[n][ks], acc[P * 2 + mi][n], 0, 0, 0);                 \
    __builtin_amdgcn_s_setprio(0);                                             \
    __builtin_amdgcn_s_barrier();                                              \
  }

  const int nIt = K >> 7;

  stageB(0, 0, 0); stageB(0, 1, 0);
  stageA(0, 0, 0); stageA(0, 1, 0);
  stageB(1, 0, 64); stageB(1, 1, 64);
  stageA(1, 0, 64);
  WAITV(5);
  __builtin_amdgcn_s_barrier();

  int k0 = 0;
  for (int it = 0; it < nIt - 1; ++it, k0 += 128) {
    PH128(0, 0, stageA(1, 1, k0 + 64), );                               // p1
    PH128(0, 1, stageB(0, 0, k0 + 128), WAITV(8));                      // p2
    PH128(0, 2, (stageB(0, 1, k0 + 128), stageA(0, 0, k0 + 128)), );    // p3
    PH128(0, 3, , WAITV(6));                                            // p4
    PH128(1, 0, stageA(0, 1, k0 + 128), );                              // p5
    PH128(1, 1, stageB(1, 0, k0 + 192), WAITV(8));                      // p6
    PH128(1, 2, (stageB(1, 1, k0 + 192), stageA(1, 0, k0 + 192)), );    // p7
    PH128(1, 3, , WAITV(6));                                            // p8
  }
  PH128(0, 0, stageA(1, 1, k0 + 64), );
  PH128(0, 1, , WAITV(6));
  PH128(0, 2, , );
  PH128(0, 3, , WAITV(1));
  PH128(1, 0, , );
  PH128(1, 1, , WAITV(0));
  PH128(1, 2, , );
  PH128(1, 3, , );
#undef PH128
#undef WAITV

  const int orow = by * 128 + (lane >> 4) * 4;
  const int ocol = nOff + bx * 256 + wn + lr;
#pragma unroll
  for (int m = 0; m < 8; ++m)
#pragma unroll
    for (int n = 0; n < 2; ++n)
#pragma unroll
      for (int r = 0; r < 4; ++r)
        C[(size_t)(orow + m * 16 + r) * Ncols + (ocol + n * 16)] = (OutT)acc[m][n][r];
}

// ---------------- rope + rms-norm, in-place on q,k (vectorized bf16x4) ------
// 16 lanes per row; each thread handles 4 rope pairs (d, d+64) via bf16x4 +
// float4 table loads; rms reduce via shfl_xor 1/2/4/8 (closed within 16).
__global__ __launch_bounds__(256) void rope_rms(
    bf16* __restrict__ qkv, const float* __restrict__ cs,
    const float* __restrict__ sn, int T) {
  const int C = N_HEAD * HEAD_DIM;
  const int S = 3 * C;
  const int r = blockIdx.x * 16 + (threadIdx.x >> 4);  // global row id
  const int l = threadIdx.x & 15;
  const int bt = r >> 5;
  const int rem = r & 31;
  const int z = rem >> 4;   // 0 = q, 1 = k
  const int h = rem & 15;
  const int t = bt % T;
  bf16* p = qkv + (size_t)bt * S + z * C + h * HEAD_DIM;
  // q: 1.2 * 0.08838834764831845 * 1.4426950408889634 (exp2-domain softmax)
  const float oscale = z ? 1.2f : 0.15302091809294977f;

  const float4 c4 = *reinterpret_cast<const float4*>(cs + t * 64 + l * 4);
  const float4 s4 = *reinterpret_cast<const float4*>(sn + t * 64 + l * 4);
  const float cj[4] = {c4.x, c4.y, c4.z, c4.w};
  const float sj[4] = {s4.x, s4.y, s4.z, s4.w};
  const bf16x4 xa = *reinterpret_cast<const bf16x4*>(p + l * 4);
  const bf16x4 xb = *reinterpret_cast<const bf16x4*>(p + 64 + l * 4);

  float r1[4], r2[4];
  float ss = 0.f;
#pragma unroll
  for (int j = 0; j < 4; ++j) {
    const float x1 = (float)xa[j];
    const float x2 = (float)xb[j];
    r1[j] = x1 * cj[j] + x2 * sj[j];
    r2[j] = x2 * cj[j] - x1 * sj[j];
    ss += r1[j] * r1[j] + r2[j] * r2[j];
  }
#pragma unroll
  for (int m = 1; m < 16; m <<= 1) ss += __shfl_xor(ss, m);
  const float sc = oscale * rsqrtf(ss * (1.0f / 128.0f) + 1e-6f);
  bf16x4 o1, o2;
#pragma unroll
  for (int j = 0; j < 4; ++j) {
    o1[j] = (bf16)(r1[j] * sc);
    o2[j] = (bf16)(r2[j] * sc);
  }
  *reinterpret_cast<bf16x4*>(p + l * 4) = o1;
  *reinterpret_cast<bf16x4*>(p + 64 + l * 4) = o2;
}

// ---------------- gate + transpose: vT[b][h][d][t] = v[b][t][h][d] + gate*ve --
__global__ __launch_bounds__(256) void gate_transpose(
    const bf16* __restrict__ qkv, const float* __restrict__ x,
    const float* __restrict__ ve, const float* __restrict__ Wg,
    bf16* __restrict__ vT, int T) {
  const int C = N_HEAD * HEAD_DIM;
  const int S = 3 * C;
  const int t0 = blockIdx.x * 64;
  const int c0 = blockIdx.y * 64;
  const int b = blockIdx.z;
  const int h = c0 >> 7;

  __shared__ float gs[64];
  __shared__ __align__(16) bf16 tile[64][72];

  if (threadIdx.x < 64) {
    const float* xr = x + (size_t)(b * T + t0 + threadIdx.x) * C;
    float a = 0.f;
#pragma unroll
    for (int j = 0; j < 12; ++j) a += xr[j] * Wg[h * 12 + j];
    gs[threadIdx.x] = 3.f / (1.f + __expf(-a));
  }
  __syncthreads();

  {
    const int r = threadIdx.x >> 2;
    const int cc = (threadIdx.x & 3) * 16;
    const size_t vrow = (size_t)(b * T + t0 + r) * S + 2 * C + c0 + cc;
    const size_t erow = (size_t)(b * T + t0 + r) * C + c0 + cc;
    bf16x8 a0 = *reinterpret_cast<const bf16x8*>(qkv + vrow);
    bf16x8 a1 = *reinterpret_cast<const bf16x8*>(qkv + vrow + 8);
    const float4* vep = reinterpret_cast<const float4*>(ve + erow);
    const float4 e0 = vep[0], e1 = vep[1], e2 = vep[2], e3 = vep[3];
    const float ev[16] = {e0.x, e0.y, e0.z, e0.w, e1.x, e1.y, e1.z, e1.w,
                          e2.x, e2.y, e2.z, e2.w, e3.x, e3.y, e3.z, e3.w};
    const float g = gs[r];
    bf16x8 o0, o1;
#pragma unroll
    for (int i = 0; i < 8; ++i) o0[i] = (bf16)((float)a0[i] + g * ev[i]);
#pragma unroll
    for (int i = 0; i < 8; ++i) o1[i] = (bf16)((float)a1[i] + g * ev[8 + i]);
    *reinterpret_cast<bf16x8*>(&tile[r][cc]) = o0;
    *reinterpret_cast<bf16x8*>(&tile[r][cc + 8]) = o1;
  }
  __syncthreads();
  {
    const int dr = threadIdx.x >> 2;        // col of tile = d offset
    const int tc = (threadIdx.x & 3) * 16;  // row of tile = t offset
    bf16x8 o0, o1;
#pragma unroll
    for (int i = 0; i < 8; ++i) o0[i] = tile[tc + i][dr];
#pragma unroll
    for (int i = 0; i < 8; ++i) o1[i] = tile[tc + 8 + i][dr];
    const size_t orow =
        ((size_t)((b * N_HEAD + h) * HEAD_DIM) + (c0 & 127) + dr) * T + t0 + tc;
    *reinterpret_cast<bf16x8*>(vT + orow) = o0;
    *reinterpret_cast<bf16x8*>(vT + orow + 8) = o1;
  }
}

// ---------------- flash attention, sliding window, LDS-staged --------------
// Round-5: 64-row q-blocks (1024 blocks), one 16-row tile per wave, 40 KB LDS
// -> 4 blocks/CU co-resident (16 waves/CU, 2x TLP vs round 4's 2 blocks).
// Same T2 XOR-swizzled LDS (conflicts ~0) and reg-prefetch double buffer.
__global__ __launch_bounds__(256, 4) void attn(
    const bf16* __restrict__ qkv, const bf16* __restrict__ vT,
    bf16* __restrict__ y, const int* __restrict__ wptr, int T, int B) {
  const int C = N_HEAD * HEAD_DIM;
  const int S = 3 * C;
  const int nq = T >> 6;                       // 64-row q-blocks per (b,h)
  const int ppx = (B * N_HEAD) >> 3;           // (b,h) pairs per XCD
  const int bid = blockIdx.x;
  const int xcd = bid & 7;
  const int sl = bid >> 3;
  const int pair = xcd * ppx + sl / nq;
  const int qi = sl % nq;
  const int b = pair / N_HEAD;
  const int h = pair % N_HEAD;
  const int qb = qi * 64;

  const int tid = threadIdx.x;
  const int wave = tid >> 6;
  const int lane = tid & 63;
  const int lm = lane & 15;
  const int quad = lane >> 4;
  const int lmw = (lm & 7) << 3;  // read-side swizzle XOR (elem units)

  const int w = wptr[0];
  const int W = (w > 0 && w < T) ? w : (1 << 30);

  __shared__ __align__(16) bf16 Ks[64][128];    // [key][d]      16 KB
  __shared__ __align__(16) bf16 Vs[128][64];    // [d][key]      16 KB
  __shared__ __align__(16) bf16 Pb[4][16][64];  // [wave][q][k]   8 KB

  const bf16* kb = qkv + (size_t)b * T * S + C + (size_t)h * HEAD_DIM;
  const bf16* vb = vT + (size_t)((b * N_HEAD + h) * HEAD_DIM) * T;  // [128][T]

  const int qt = qb + wave * 16;
  const int qr = qt + lm;  // this lane's q row (softmax owner)
  bf16x8 qf[4];
  {
    const bf16* qrow = qkv + (size_t)(b * T + qr) * S + h * HEAD_DIM;
#pragma unroll
    for (int c = 0; c < 4; ++c)
      qf[c] = *reinterpret_cast<const bf16x8*>(qrow + c * 32 + quad * 8);
  }

  float mrun = -1e30f, lrun = 0.f;
  f32x4 oacc[8] = {};

  int kstart = qb - W;
  if (kstart < 0) kstart = 0;
  kstart &= ~63;
  const int kend = qb;  // last chunk start

  const int sr = tid >> 2;        // staging row 0..63
  const int s4 = (tid & 3) * 8;   // element offset of this thread's 16B unit
  const int swz = (sr & 7) << 3;  // staging-write swizzle XOR

  bf16x8 kpre[4], vpre[4];
  {
    const bf16* kr = kb + (size_t)(kstart + sr) * S;
#pragma unroll
    for (int c = 0; c < 4; ++c)
      kpre[c] = *reinterpret_cast<const bf16x8*>(kr + c * 32 + s4);
#pragma unroll
    for (int c2 = 0; c2 < 2; ++c2)
#pragma unroll
      for (int i = 0; i < 2; ++i)
        vpre[c2 * 2 + i] = *reinterpret_cast<const bf16x8*>(
            vb + (size_t)(i * 64 + sr) * T + kstart + c2 * 32 + s4);
  }

  for (int kc = kstart; kc <= kend; kc += 64) {
    __syncthreads();
    // commit prefetched chunk (swizzled linear ds_write, conflict-free)
#pragma unroll
    for (int c = 0; c < 4; ++c)
      *reinterpret_cast<bf16x8*>(&Ks[sr][(c * 32 + s4) ^ swz]) = kpre[c];
#pragma unroll
    for (int c2 = 0; c2 < 2; ++c2)
#pragma unroll
      for (int i = 0; i < 2; ++i)
        *reinterpret_cast<bf16x8*>(&Vs[i * 64 + sr][(c2 * 32 + s4) ^ swz]) =
            vpre[c2 * 2 + i];
    __syncthreads();

    // issue next chunk's global loads before compute
    if (kc + 64 <= kend) {
      const int kc2 = kc + 64;
      const bf16* kr = kb + (size_t)(kc2 + sr) * S;
#pragma unroll
      for (int c = 0; c < 4; ++c)
        kpre[c] = *reinterpret_cast<const bf16x8*>(kr + c * 32 + s4);
#pragma unroll
      for (int c2 = 0; c2 < 2; ++c2)
#pragma unroll
        for (int i = 0; i < 2; ++i)
          vpre[c2 * 2 + i] = *reinterpret_cast<const bf16x8*>(
              vb + (size_t)(i * 64 + sr) * T + kc2 + c2 * 32 + s4);
    }

    if (kc <= qt + 15 && kc + 63 >= qt - W) {
      // S^T[key][q], 64 keys x 16 q
      f32x4 st[4] = {};
#pragma unroll
      for (int g = 0; g < 4; ++g)
#pragma unroll
        for (int c = 0; c < 4; ++c) {
          const bf16x8 kf = *reinterpret_cast<const bf16x8*>(
              &Ks[g * 16 + lm][(c * 32 + quad * 8) ^ lmw]);
          st[g] = __builtin_amdgcn_mfma_f32_16x16x32_bf16(kf, qf[c], st[g], 0, 0, 0);
        }
      // mask + row max
      float mx = -1e30f;
#pragma unroll
      for (int g = 0; g < 4; ++g)
#pragma unroll
        for (int r = 0; r < 4; ++r) {
          const int key = kc + g * 16 + quad * 4 + r;
          const bool valid = (unsigned)(qr - key) <= (unsigned)W;
          st[g][r] = valid ? st[g][r] : -1e30f;
          mx = fmaxf(mx, st[g][r]);
        }
      mx = fmaxf(mx, __shfl_xor(mx, 16));
      mx = fmaxf(mx, __shfl_xor(mx, 32));
      float alpha = 1.f;
      if (!__all(mx <= mrun)) {
        const float mnew = fmaxf(mrun, mx);
        alpha = __builtin_amdgcn_exp2f(mrun - mnew);
        mrun = mnew;
#pragma unroll
        for (int dc = 0; dc < 8; ++dc)
#pragma unroll
          for (int r = 0; r < 4; ++r) oacc[dc][r] *= alpha;
      }
      float rs = 0.f;
#pragma unroll
      for (int g = 0; g < 4; ++g) {
        bf16x4 pk;
#pragma unroll
        for (int r = 0; r < 4; ++r) {
          const float p = __builtin_amdgcn_exp2f(st[g][r] - mrun);
          rs += p;
          pk[r] = (bf16)p;
        }
        *reinterpret_cast<bf16x4*>(
            &Pb[wave][lm][((g * 16 + (quad >> 1) * 8) ^ lmw) + (quad & 1) * 4]) = pk;
      }
      rs += __shfl_xor(rs, 16);
      rs += __shfl_xor(rs, 32);
      lrun = lrun * alpha + rs;
      // O^T += V^T * P^T
#pragma unroll
      for (int c2 = 0; c2 < 2; ++c2) {
        const bf16x8 pf = *reinterpret_cast<const bf16x8*>(
            &Pb[wave][lm][(c2 * 32 + quad * 8) ^ lmw]);
#pragma unroll
        for (int dc = 0; dc < 8; ++dc) {
          const bf16x8 vf = *reinterpret_cast<const bf16x8*>(
              &Vs[dc * 16 + lm][(c2 * 32 + quad * 8) ^ lmw]);
          oacc[dc] = __builtin_amdgcn_mfma_f32_16x16x32_bf16(vf, pf, oacc[dc], 0, 0, 0);
        }
      }
    }
  }

  {
    const float inv = 1.f / lrun;
    bf16* yr = y + (size_t)(b * T + qr) * C + h * HEAD_DIM;
#pragma unroll
    for (int dc = 0; dc < 8; ++dc) {
      bf16x4 o;
#pragma unroll
      for (int r = 0; r < 4; ++r) o[r] = (bf16)(oacc[dc][r] * inv);
      *reinterpret_cast<bf16x4*>(yr + dc * 16 + quad * 4) = o;
    }
  }
}

extern "C" void kernel_launch(void* const* d_in, const int* in_sizes, int n_in,
                              void* d_out, int out_size, void* d_ws, size_t ws_size,
                              hipStream_t stream) {
  const float* x  = (const float*)d_in[0];
  const float* ve = (const float*)d_in[1];
  const float* Wq = (const float*)d_in[2];
  const float* Wk = (const float*)d_in[3];
  const float* Wv = (const float*)d_in[4];
  const float* Wp = (const float*)d_in[5];
  const float* Wg = (const float*)d_in[6];
  const float* cs = (const float*)d_in[7];
  const float* sn = (const float*)d_in[8];
  const int*   wl = (const int*)d_in[9];
  float* out = (float*)d_out;

  const int C = N_HEAD * HEAD_DIM;       // 2048
  const int T = in_sizes[7] / (HEAD_DIM / 2);
  const int B = in_sizes[0] / (T * C);
  const int M = B * T;

  bf16* xb   = (bf16*)d_ws;                    // [M][C]
  bf16* wqkv = xb   + (size_t)M * C;           // [3C][C] (Wq|Wk|Wv rows)
  bf16* wpb  = wqkv + (size_t)3 * C * C;       // [C][C]
  bf16* qkv  = wpb  + (size_t)C * C;           // [M][3C]
  bf16* ybuf = qkv  + (size_t)3 * M * C;       // [M][C]
  bf16* vTb  = xb;  // xb dead after QKV GEMM; reuse for V^T [B][H][128][T]

  const int nx4 = M * C / 4, nw4 = C * C / 4;
  cvt_all<<<dim3((nx4 + 255) / 256, 1, 5), 256, 0, stream>>>(
      x, Wq, Wk, Wv, Wp, xb, wqkv, wpb, nx4, nw4);

  // QKV split for exact-round grids (256 CUs, 1 block/CU):
  // part 1: Q|K cols 0..4095  -> gemm256, (4096/256)*16 = 256 blocks
  // part 2: V  cols 4096..6143 -> gemm128, (4096/128)*8 = 256 blocks
  gemm256<<<dim3((M / 256) * 16), 512, 0, stream>>>(xb, wqkv, qkv, M, 3 * C, C);
  gemm128<bf16><<<dim3((M / 128) * 8), 512, 0, stream>>>(
      xb, wqkv, qkv, M, 3 * C, C, 2 * C);

  rope_rms<<<dim3(M * 2), 256, 0, stream>>>(qkv, cs, sn, T);
  gate_transpose<<<dim3(T / 64, C / 64, B), 256, 0, stream>>>(qkv, x, ve, Wg, vTb, T);
  attn<<<dim3(B * N_HEAD * (T / 64)), 256, 0, stream>>>(qkv, vTb, ybuf, wl, T, B);

  // projection: [M,2048] = ybuf * wpb^T -> gemm128<float>, 32*8 = 256 blocks
  gemm128<float><<<dim3((M / 128) * (C / 256)), 512, 0, stream>>>(
      ybuf, wpb, out, M, C, C, 0);
}

// Round 6
// 379.255 us; speedup vs baseline: 1.1094x; 1.1094x over previous
//
#include <hip/hip_runtime.h>
#include <hip/hip_bf16.h>
#include <cstdint>

#define N_HEAD 16
#define HEAD_DIM 128

typedef __bf16 bf16;
typedef __bf16 bf16x8 __attribute__((ext_vector_type(8)));
typedef __bf16 bf16x4 __attribute__((ext_vector_type(4)));
typedef float f32x4 __attribute__((ext_vector_type(4)));

// async global->LDS 16B (per-lane lds addr must be base + lane*16)
__device__ __forceinline__ void gload_lds16(const void* g, void* l) {
  auto gp = reinterpret_cast<const __attribute__((address_space(1))) char*>(
      reinterpret_cast<uintptr_t>(g));
  auto lp = reinterpret_cast<__attribute__((address_space(3))) char*>(
      reinterpret_cast<uintptr_t>(l));
  __builtin_amdgcn_global_load_lds(gp, lp, 16, 0, 0);
}

// ------- fp32 -> bf16 convert, all 5 tensors in one launch (z selects) ------
__global__ __launch_bounds__(256) void cvt_all(
    const float* __restrict__ x, const float* __restrict__ Wq,
    const float* __restrict__ Wk, const float* __restrict__ Wv,
    const float* __restrict__ Wp, bf16* __restrict__ xb,
    bf16* __restrict__ wqkv, bf16* __restrict__ wpb, int nx4, int nw4) {
  const int z = blockIdx.z;
  const float* in;
  bf16* out;
  int n4;
  if (z == 0)      { in = x;  out = xb;  n4 = nx4; }
  else if (z == 1) { in = Wq; out = wqkv;                     n4 = nw4; }
  else if (z == 2) { in = Wk; out = wqkv + (size_t)nw4 * 4;   n4 = nw4; }
  else if (z == 3) { in = Wv; out = wqkv + (size_t)nw4 * 8;   n4 = nw4; }
  else             { in = Wp; out = wpb;  n4 = nw4; }
  const int i = blockIdx.x * 256 + threadIdx.x;
  if (i >= n4) return;
  const float4 f = reinterpret_cast<const float4*>(in)[i];
  bf16x4 o;
  o.x = (bf16)f.x; o.y = (bf16)f.y; o.z = (bf16)f.z; o.w = (bf16)f.w;
  reinterpret_cast<bf16x4*>(out)[i] = o;
}

// ---------------- 256x256 8-phase GEMM (bf16 in/out) ------------------------
// BM=BN=256, BK=64, 512 threads (8 waves = 2Mx4N), per-wave C = 128x64.
// Verified round 2: bank-conflict 0. Grid = (M/256)*NT blocks, NT columns.
__global__ __launch_bounds__(512, 2) void gemm256(
    const bf16* __restrict__ A, const bf16* __restrict__ Bt,
    bf16* __restrict__ C, int M, int N, int K) {
  __shared__ __align__(16) char sA[2][32768];
  __shared__ __align__(16) char sB[2][32768];

  const int nwgy = M >> 8;
  const int nwg = gridDim.x;
  const int q8 = nwg >> 3;
  const int wgid = (blockIdx.x & 7) * q8 + (blockIdx.x >> 3);
  const int by = wgid % nwgy;
  const int bx = wgid / nwgy;

  const int tid = threadIdx.x;
  const int lane = tid & 63;
  const int wave = tid >> 6;
  const int wm = (wave >> 2) << 7;   // 0 / 128
  const int wn = (wave & 3) << 6;    // 0..192
  const int lr = lane & 15;
  const int lk16 = (lane >> 4) << 4; // quad's 16B k-group
  const int sx = (lr & 7) << 4;      // read-side swizzle XOR (row&7)<<4

  const bf16* Ab = A + (size_t)by * 256 * K;
  const bf16* Bb = Bt + (size_t)bx * 256 * K;

  int srow[2], scol[2];
#pragma unroll
  for (int pp = 0; pp < 2; ++pp) {
    const int o = pp * 8192 + tid * 16;
    srow[pp] = o >> 7;
    scol[pp] = (o & 127) ^ ((srow[pp] & 7) << 4);
  }

  auto stageA = [&](int buf, int half, int k0) {
#pragma unroll
    for (int pp = 0; pp < 2; ++pp)
      gload_lds16(Ab + (size_t)(half * 128 + srow[pp]) * K + k0 + (scol[pp] >> 1),
                  sA[buf] + half * 16384 + pp * 8192 + tid * 16);
  };
  auto stageB = [&](int buf, int half, int k0) {
#pragma unroll
    for (int pp = 0; pp < 2; ++pp)
      gload_lds16(Bb + (size_t)(half * 128 + srow[pp]) * K + k0 + (scol[pp] >> 1),
                  sB[buf] + half * 16384 + pp * 8192 + tid * 16);
  };

  f32x4 acc[8][4] = {};
  bf16x8 bF[4][2];

#define VMCNT4                                             \
  asm volatile("s_waitcnt vmcnt(4)" ::: "memory");         \
  __builtin_amdgcn_sched_barrier(0)
#define VMCNT0                                             \
  asm volatile("s_waitcnt vmcnt(0)" ::: "memory");         \
  __builtin_amdgcn_sched_barrier(0)

#define PHASE(BUF, P, STAGE, WAIT)                                             \
  {                                                                            \
    bf16x8 aF[2][2];                                                           \
    if (P == 0) {                                                              \
      _Pragma("unroll") for (int n = 0; n < 4; ++n)                            \
      _Pragma("unroll") for (int ks = 0; ks < 2; ++ks)                         \
        bF[n][ks] = *reinterpret_cast<const bf16x8*>(                          \
            sB[BUF] + (wn + n * 16 + lr) * 128 + ((ks * 64 + lk16) ^ sx));     \
    }                                                                          \
    _Pragma("unroll") for (int mi = 0; mi < 2; ++mi)                           \
    _Pragma("unroll") for (int ks = 0; ks < 2; ++ks)                           \
      aF[mi][ks] = *reinterpret_cast<const bf16x8*>(                           \
          sA[BUF] + (wm + (P * 2 + mi) * 16 + lr) * 128 +                      \
          ((ks * 64 + lk16) ^ sx));                                            \
    STAGE;                                                                     \
    WAIT;                                                                      \
    __builtin_amdgcn_s_barrier();                                              \
    __builtin_amdgcn_s_setprio(1);                                             \
    _Pragma("unroll") for (int ks = 0; ks < 2; ++ks)                           \
    _Pragma("unroll") for (int mi = 0; mi < 2; ++mi)                           \
    _Pragma("unroll") for (int n = 0; n < 4; ++n)                              \
      acc[P * 2 + mi][n] = __builtin_amdgcn_mfma_f32_16x16x32_bf16(            \
          aF[mi][ks], bF[n][ks], acc[P * 2 + mi][n], 0, 0, 0);                 \
    __builtin_amdgcn_s_setprio(0);                                             \
    __builtin_amdgcn_s_barrier();                                              \
  }

  const int nIt = K >> 7;  // 2 K-steps (BK=64) per iteration

  stageB(0, 0, 0); stageB(0, 1, 0);
  stageA(0, 0, 0); stageA(0, 1, 0);
  stageB(1, 0, 64); stageB(1, 1, 64);
  VMCNT4;
  __builtin_amdgcn_s_barrier();

  int k0 = 0;
  for (int it = 0; it < nIt - 1; ++it, k0 += 128) {
    PHASE(0, 0, stageA(1, 0, k0 + 64), );
    PHASE(0, 1, stageA(1, 1, k0 + 64), );
    PHASE(0, 2, stageB(0, 0, k0 + 128), );
    PHASE(0, 3, stageB(0, 1, k0 + 128), VMCNT4);
    PHASE(1, 0, stageA(0, 0, k0 + 128), );
    PHASE(1, 1, stageA(0, 1, k0 + 128), );
    PHASE(1, 2, stageB(1, 0, k0 + 192), );
    PHASE(1, 3, stageB(1, 1, k0 + 192), VMCNT4);
  }
  PHASE(0, 0, stageA(1, 0, k0 + 64), );
  PHASE(0, 1, stageA(1, 1, k0 + 64), );
  PHASE(0, 2, , );
  PHASE(0, 3, , VMCNT0);
  PHASE(1, 0, , );
  PHASE(1, 1, , );
  PHASE(1, 2, , );
  PHASE(1, 3, , );
#undef PHASE
#undef VMCNT4
#undef VMCNT0

  const int orow = by * 256 + wm + (lane >> 4) * 4;
  const int ocol = bx * 256 + wn + lr;
#pragma unroll
  for (int m = 0; m < 8; ++m)
#pragma unroll
    for (int n = 0; n < 4; ++n)
#pragma unroll
      for (int r = 0; r < 4; ++r)
        C[(size_t)(orow + m * 16 + r) * N + (ocol + n * 16)] = (bf16)acc[m][n][r];
}

// ---------------- 128x256 8-phase GEMM (templated OutT) ---------------------
// BM=128, BN=256, BK=64, 512 threads (8 waves, 1Mx8N: per-wave C = 128x32).
// LDS 96 KiB. Deep stage/wait ledger (verified round 3).
template <typename OutT>
__global__ __launch_bounds__(512, 2) void gemm128(
    const bf16* __restrict__ A, const bf16* __restrict__ Bt,
    OutT* __restrict__ C, int M, int Ncols, int K, int nOff) {
  __shared__ __align__(16) char sA[2][16384];
  __shared__ __align__(16) char sB[2][32768];

  const int nwgy = M >> 7;
  const int nwg = gridDim.x;
  const int q8 = nwg >> 3;
  const int wgid = (blockIdx.x & 7) * q8 + (blockIdx.x >> 3);
  const int by = wgid % nwgy;
  const int bx = wgid / nwgy;

  const int tid = threadIdx.x;
  const int lane = tid & 63;
  const int wave = tid >> 6;
  const int wn = wave << 5;          // 0..224
  const int lr = lane & 15;
  const int lk16 = (lane >> 4) << 4;
  const int sx = (lr & 7) << 4;

  const bf16* Ab = A + (size_t)by * 128 * K;
  const bf16* Bb = Bt + (size_t)(nOff + bx * 256) * K;

  int srow[2], scol[2];
#pragma unroll
  for (int pp = 0; pp < 2; ++pp) {
    const int o = pp * 8192 + tid * 16;
    srow[pp] = o >> 7;
    scol[pp] = (o & 127) ^ ((srow[pp] & 7) << 4);
  }

  auto stageB = [&](int buf, int half, int k0) {
#pragma unroll
    for (int pp = 0; pp < 2; ++pp)
      gload_lds16(Bb + (size_t)(half * 128 + srow[pp]) * K + k0 + (scol[pp] >> 1),
                  sB[buf] + half * 16384 + pp * 8192 + tid * 16);
  };
  auto stageA = [&](int buf, int half, int k0) {
    const int o = tid * 16;
    const int row = o >> 7;  // 0..63
    const int col = (o & 127) ^ ((row & 7) << 4);
    gload_lds16(Ab + (size_t)(half * 64 + row) * K + k0 + (col >> 1),
                sA[buf] + half * 8192 + o);
  };

  f32x4 acc[8][2] = {};
  bf16x8 bF[2][2];

#define WAITV(n)                                               \
  asm volatile("s_waitcnt vmcnt(" #n ")" ::: "memory");        \
  __builtin_amdgcn_sched_barrier(0)

#define PH128(BUF, P, STAGE, WAIT)                                             \
  {                                                                            \
    bf16x8 aF[2][2];                                                           \
    if (P == 0) {                                                              \
      _Pragma("unroll") for (int n = 0; n < 2; ++n)                            \
      _Pragma("unroll") for (int ks = 0; ks < 2; ++ks)                         \
        bF[n][ks] = *reinterpret_cast<const bf16x8*>(                          \
            sB[BUF] + (wn + n * 16 + lr) * 128 + ((ks * 64 + lk16) ^ sx));     \
    }                                                                          \
    _Pragma("unroll") for (int mi = 0; mi < 2; ++mi)                           \
    _Pragma("unroll") for (int ks = 0; ks < 2; ++ks)                           \
      aF[mi][ks] = *reinterpret_cast<const bf16x8*>(                           \
          sA[BUF] + ((P * 2 + mi) * 16 + lr) * 128 + ((ks * 64 + lk16) ^ sx)); \
    STAGE;                                                                     \
    WAIT;                                                                      \
    __builtin_amdgcn_s_barrier();                                              \
    __builtin_amdgcn_s_setprio(1);                                             \
    _Pragma("unroll") for (int ks = 0; ks < 2; ++ks)                           \
    _Pragma("unroll") for (int mi = 0; mi < 2; ++mi)                           \
    _Pragma("unroll") for (int n = 0; n < 2; ++n)                              \
      acc[P * 2 + mi][n] = __builtin_amdgcn_mfma_f32_16x16x32_bf16(            \
          aF[mi][ks], bF[n][ks], acc[P * 2 + mi][n], 0, 0, 0);                 \
    __builtin_amdgcn_s_setprio(0);                                             \
    __builtin_amdgcn_s_barrier();                                              \
  }

  const int nIt = K >> 7;

  stageB(0, 0, 0); stageB(0, 1, 0);
  stageA(0, 0, 0); stageA(0, 1, 0);
  stageB(1, 0, 64); stageB(1, 1, 64);
  stageA(1, 0, 64);
  WAITV(5);
  __builtin_amdgcn_s_barrier();

  int k0 = 0;
  for (int it = 0; it < nIt - 1; ++it, k0 += 128) {
    PH128(0, 0, stageA(1, 1, k0 + 64), );                               // p1
    PH128(0, 1, stageB(0, 0, k0 + 128), WAITV(8));                      // p2
    PH128(0, 2, (stageB(0, 1, k0 + 128), stageA(0, 0, k0 + 128)), );    // p3
    PH128(0, 3, , WAITV(6));                                            // p4
    PH128(1, 0, stageA(0, 1, k0 + 128), );                              // p5
    PH128(1, 1, stageB(1, 0, k0 + 192), WAITV(8));                      // p6
    PH128(1, 2, (stageB(1, 1, k0 + 192), stageA(1, 0, k0 + 192)), );    // p7
    PH128(1, 3, , WAITV(6));                                            // p8
  }
  PH128(0, 0, stageA(1, 1, k0 + 64), );
  PH128(0, 1, , WAITV(6));
  PH128(0, 2, , );
  PH128(0, 3, , WAITV(1));
  PH128(1, 0, , );
  PH128(1, 1, , WAITV(0));
  PH128(1, 2, , );
  PH128(1, 3, , );
#undef PH128
#undef WAITV

  const int orow = by * 128 + (lane >> 4) * 4;
  const int ocol = nOff + bx * 256 + wn + lr;
#pragma unroll
  for (int m = 0; m < 8; ++m)
#pragma unroll
    for (int n = 0; n < 2; ++n)
#pragma unroll
      for (int r = 0; r < 4; ++r)
        C[(size_t)(orow + m * 16 + r) * Ncols + (ocol + n * 16)] = (OutT)acc[m][n][r];
}

// ---------------- rope + rms-norm, in-place on q,k (vectorized bf16x4) ------
__global__ __launch_bounds__(256) void rope_rms(
    bf16* __restrict__ qkv, const float* __restrict__ cs,
    const float* __restrict__ sn, int T) {
  const int C = N_HEAD * HEAD_DIM;
  const int S = 3 * C;
  const int r = blockIdx.x * 16 + (threadIdx.x >> 4);  // global row id
  const int l = threadIdx.x & 15;
  const int bt = r >> 5;
  const int rem = r & 31;
  const int z = rem >> 4;   // 0 = q, 1 = k
  const int h = rem & 15;
  const int t = bt % T;
  bf16* p = qkv + (size_t)bt * S + z * C + h * HEAD_DIM;
  // q: 1.2 * 0.08838834764831845 * 1.4426950408889634 (exp2-domain softmax)
  const float oscale = z ? 1.2f : 0.15302091809294977f;

  const float4 c4 = *reinterpret_cast<const float4*>(cs + t * 64 + l * 4);
  const float4 s4 = *reinterpret_cast<const float4*>(sn + t * 64 + l * 4);
  const float cj[4] = {c4.x, c4.y, c4.z, c4.w};
  const float sj[4] = {s4.x, s4.y, s4.z, s4.w};
  const bf16x4 xa = *reinterpret_cast<const bf16x4*>(p + l * 4);
  const bf16x4 xb = *reinterpret_cast<const bf16x4*>(p + 64 + l * 4);

  float r1[4], r2[4];
  float ss = 0.f;
#pragma unroll
  for (int j = 0; j < 4; ++j) {
    const float x1 = (float)xa[j];
    const float x2 = (float)xb[j];
    r1[j] = x1 * cj[j] + x2 * sj[j];
    r2[j] = x2 * cj[j] - x1 * sj[j];
    ss += r1[j] * r1[j] + r2[j] * r2[j];
  }
#pragma unroll
  for (int m = 1; m < 16; m <<= 1) ss += __shfl_xor(ss, m);
  const float sc = oscale * rsqrtf(ss * (1.0f / 128.0f) + 1e-6f);
  bf16x4 o1, o2;
#pragma unroll
  for (int j = 0; j < 4; ++j) {
    o1[j] = (bf16)(r1[j] * sc);
    o2[j] = (bf16)(r2[j] * sc);
  }
  *reinterpret_cast<bf16x4*>(p + l * 4) = o1;
  *reinterpret_cast<bf16x4*>(p + 64 + l * 4) = o2;
}

// ---------------- gate + transpose: vT[b][h][d][t] = v[b][t][h][d] + gate*ve --
__global__ __launch_bounds__(256) void gate_transpose(
    const bf16* __restrict__ qkv, const float* __restrict__ x,
    const float* __restrict__ ve, const float* __restrict__ Wg,
    bf16* __restrict__ vT, int T) {
  const int C = N_HEAD * HEAD_DIM;
  const int S = 3 * C;
  const int t0 = blockIdx.x * 64;
  const int c0 = blockIdx.y * 64;
  const int b = blockIdx.z;
  const int h = c0 >> 7;

  __shared__ float gs[64];
  __shared__ __align__(16) bf16 tile[64][72];

  if (threadIdx.x < 64) {
    const float* xr = x + (size_t)(b * T + t0 + threadIdx.x) * C;
    float a = 0.f;
#pragma unroll
    for (int j = 0; j < 12; ++j) a += xr[j] * Wg[h * 12 + j];
    gs[threadIdx.x] = 3.f / (1.f + __expf(-a));
  }
  __syncthreads();

  {
    const int r = threadIdx.x >> 2;
    const int cc = (threadIdx.x & 3) * 16;
    const size_t vrow = (size_t)(b * T + t0 + r) * S + 2 * C + c0 + cc;
    const size_t erow = (size_t)(b * T + t0 + r) * C + c0 + cc;
    bf16x8 a0 = *reinterpret_cast<const bf16x8*>(qkv + vrow);
    bf16x8 a1 = *reinterpret_cast<const bf16x8*>(qkv + vrow + 8);
    const float4* vep = reinterpret_cast<const float4*>(ve + erow);
    const float4 e0 = vep[0], e1 = vep[1], e2 = vep[2], e3 = vep[3];
    const float ev[16] = {e0.x, e0.y, e0.z, e0.w, e1.x, e1.y, e1.z, e1.w,
                          e2.x, e2.y, e2.z, e2.w, e3.x, e3.y, e3.z, e3.w};
    const float g = gs[r];
    bf16x8 o0, o1;
#pragma unroll
    for (int i = 0; i < 8; ++i) o0[i] = (bf16)((float)a0[i] + g * ev[i]);
#pragma unroll
    for (int i = 0; i < 8; ++i) o1[i] = (bf16)((float)a1[i] + g * ev[8 + i]);
    *reinterpret_cast<bf16x8*>(&tile[r][cc]) = o0;
    *reinterpret_cast<bf16x8*>(&tile[r][cc + 8]) = o1;
  }
  __syncthreads();
  {
    const int dr = threadIdx.x >> 2;        // col of tile = d offset
    const int tc = (threadIdx.x & 3) * 16;  // row of tile = t offset
    bf16x8 o0, o1;
#pragma unroll
    for (int i = 0; i < 8; ++i) o0[i] = tile[tc + i][dr];
#pragma unroll
    for (int i = 0; i < 8; ++i) o1[i] = tile[tc + 8 + i][dr];
    const size_t orow =
        ((size_t)((b * N_HEAD + h) * HEAD_DIM) + (c0 & 127) + dr) * T + t0 + tc;
    *reinterpret_cast<bf16x8*>(vT + orow) = o0;
    *reinterpret_cast<bf16x8*>(vT + orow + 8) = o1;
  }
}

// ---------------- flash attention, sliding window, LDS-staged --------------
// Round-6: 128-row q-blocks (512 blocks, round-4 K/V traffic) but 512 threads
// / 8 waves per block, ONE 16-row tile per wave -> 2 blocks/CU = 16 waves/CU
// = 4 waves/SIMD (2x round 4's TLP) with NO extra HBM traffic. T2-swizzled
// LDS; reg-prefetch double buffer; staging split across all 8 waves.
__global__ __launch_bounds__(512, 4) void attn(
    const bf16* __restrict__ qkv, const bf16* __restrict__ vT,
    bf16* __restrict__ y, const int* __restrict__ wptr, int T, int B) {
  const int C = N_HEAD * HEAD_DIM;
  const int S = 3 * C;
  const int nq = T >> 7;                       // 128-row q-blocks per (b,h)
  const int ppx = (B * N_HEAD) >> 3;           // (b,h) pairs per XCD
  const int bid = blockIdx.x;
  const int xcd = bid & 7;
  const int sl = bid >> 3;
  const int pair = xcd * ppx + sl / nq;
  const int qi = sl % nq;
  const int b = pair / N_HEAD;
  const int h = pair % N_HEAD;
  const int qb = qi * 128;

  const int tid = threadIdx.x;
  const int wave = tid >> 6;      // 0..7
  const int lane = tid & 63;
  const int lm = lane & 15;
  const int quad = lane >> 4;
  const int lmw = (lm & 7) << 3;  // read-side swizzle XOR (elem units)

  const int w = wptr[0];
  const int W = (w > 0 && w < T) ? w : (1 << 30);

  __shared__ __align__(16) bf16 Ks[64][128];    // [key][d]      16 KB
  __shared__ __align__(16) bf16 Vs[128][64];    // [d][key]      16 KB
  __shared__ __align__(16) bf16 Pb[8][16][64];  // [wave][q][k]  16 KB

  const bf16* kb = qkv + (size_t)b * T * S + C + (size_t)h * HEAD_DIM;
  const bf16* vb = vT + (size_t)((b * N_HEAD + h) * HEAD_DIM) * T;  // [128][T]

  const int qt = qb + wave * 16;
  const int qr = qt + lm;  // this lane's q row (softmax owner)
  bf16x8 qf[4];
  {
    const bf16* qrow = qkv + (size_t)(b * T + qr) * S + h * HEAD_DIM;
#pragma unroll
    for (int c = 0; c < 4; ++c)
      qf[c] = *reinterpret_cast<const bf16x8*>(qrow + c * 32 + quad * 8);
  }

  float mrun = -1e30f, lrun = 0.f;
  f32x4 oacc[8] = {};

  int kstart = qb - W;
  if (kstart < 0) kstart = 0;
  kstart &= ~63;
  const int kend = qb + 64;  // last chunk start (covers rows up to qb+127)

  // staging split over 512 threads: K rows 0..63 x 128 elems (8 thr/row,
  // 2x16B each); V rows 0..127 x 64 elems (4 thr/row, 2x16B each).
  const int krow = tid >> 3, kc0 = (tid & 7) * 16, kswz = (krow & 7) << 3;
  const int vrow = tid >> 2, vc0 = (tid & 3) * 16, vswz = (vrow & 7) << 3;

  bf16x8 kpre[2], vpre[2];
  {
    const bf16* kr = kb + (size_t)(kstart + krow) * S + kc0;
    kpre[0] = *reinterpret_cast<const bf16x8*>(kr);
    kpre[1] = *reinterpret_cast<const bf16x8*>(kr + 8);
    const bf16* vr = vb + (size_t)vrow * T + kstart + vc0;
    vpre[0] = *reinterpret_cast<const bf16x8*>(vr);
    vpre[1] = *reinterpret_cast<const bf16x8*>(vr + 8);
  }

  for (int kc = kstart; kc <= kend; kc += 64) {
    __syncthreads();
    // commit prefetched chunk (swizzled ds_write, conflict-free)
    *reinterpret_cast<bf16x8*>(&Ks[krow][kc0 ^ kswz]) = kpre[0];
    *reinterpret_cast<bf16x8*>(&Ks[krow][(kc0 + 8) ^ kswz]) = kpre[1];
    *reinterpret_cast<bf16x8*>(&Vs[vrow][vc0 ^ vswz]) = vpre[0];
    *reinterpret_cast<bf16x8*>(&Vs[vrow][(vc0 + 8) ^ vswz]) = vpre[1];
    __syncthreads();

    // issue next chunk's global loads before compute
    if (kc + 64 <= kend) {
      const int kc2 = kc + 64;
      const bf16* kr = kb + (size_t)(kc2 + krow) * S + kc0;
      kpre[0] = *reinterpret_cast<const bf16x8*>(kr);
      kpre[1] = *reinterpret_cast<const bf16x8*>(kr + 8);
      const bf16* vr = vb + (size_t)vrow * T + kc2 + vc0;
      vpre[0] = *reinterpret_cast<const bf16x8*>(vr);
      vpre[1] = *reinterpret_cast<const bf16x8*>(vr + 8);
    }

    if (kc <= qt + 15 && kc + 63 >= qt - W) {
      // S^T[key][q], 64 keys x 16 q
      f32x4 st[4] = {};
#pragma unroll
      for (int g = 0; g < 4; ++g)
#pragma unroll
        for (int c = 0; c < 4; ++c) {
          const bf16x8 kf = *reinterpret_cast<const bf16x8*>(
              &Ks[g * 16 + lm][(c * 32 + quad * 8) ^ lmw]);
          st[g] = __builtin_amdgcn_mfma_f32_16x16x32_bf16(kf, qf[c], st[g], 0, 0, 0);
        }
      // mask + row max
      float mx = -1e30f;
#pragma unroll
      for (int g = 0; g < 4; ++g)
#pragma unroll
        for (int r = 0; r < 4; ++r) {
          const int key = kc + g * 16 + quad * 4 + r;
          const bool valid = (unsigned)(qr - key) <= (unsigned)W;
          st[g][r] = valid ? st[g][r] : -1e30f;
          mx = fmaxf(mx, st[g][r]);
        }
      mx = fmaxf(mx, __shfl_xor(mx, 16));
      mx = fmaxf(mx, __shfl_xor(mx, 32));
      float alpha = 1.f;
      if (!__all(mx <= mrun)) {
        const float mnew = fmaxf(mrun, mx);
        alpha = __builtin_amdgcn_exp2f(mrun - mnew);
        mrun = mnew;
#pragma unroll
        for (int dc = 0; dc < 8; ++dc)
#pragma unroll
          for (int r = 0; r < 4; ++r) oacc[dc][r] *= alpha;
      }
      float rs = 0.f;
#pragma unroll
      for (int g = 0; g < 4; ++g) {
        bf16x4 pk;
#pragma unroll
        for (int r = 0; r < 4; ++r) {
          const float p = __builtin_amdgcn_exp2f(st[g][r] - mrun);
          rs += p;
          pk[r] = (bf16)p;
        }
        *reinterpret_cast<bf16x4*>(
            &Pb[wave][lm][((g * 16 + (quad >> 1) * 8) ^ lmw) + (quad & 1) * 4]) = pk;
      }
      rs += __shfl_xor(rs, 16);
      rs += __shfl_xor(rs, 32);
      lrun = lrun * alpha + rs;
      // O^T += V^T * P^T
#pragma unroll
      for (int c2 = 0; c2 < 2; ++c2) {
        const bf16x8 pf = *reinterpret_cast<const bf16x8*>(
            &Pb[wave][lm][(c2 * 32 + quad * 8) ^ lmw]);
#pragma unroll
        for (int dc = 0; dc < 8; ++dc) {
          const bf16x8 vf = *reinterpret_cast<const bf16x8*>(
              &Vs[dc * 16 + lm][(c2 * 32 + quad * 8) ^ lmw]);
          oacc[dc] = __builtin_amdgcn_mfma_f32_16x16x32_bf16(vf, pf, oacc[dc], 0, 0, 0);
        }
      }
    }
  }

  {
    const float inv = 1.f / lrun;
    bf16* yr = y + (size_t)(b * T + qr) * C + h * HEAD_DIM;
#pragma unroll
    for (int dc = 0; dc < 8; ++dc) {
      bf16x4 o;
#pragma unroll
      for (int r = 0; r < 4; ++r) o[r] = (bf16)(oacc[dc][r] * inv);
      *reinterpret_cast<bf16x4*>(yr + dc * 16 + quad * 4) = o;
    }
  }
}

extern "C" void kernel_launch(void* const* d_in, const int* in_sizes, int n_in,
                              void* d_out, int out_size, void* d_ws, size_t ws_size,
                              hipStream_t stream) {
  const float* x  = (const float*)d_in[0];
  const float* ve = (const float*)d_in[1];
  const float* Wq = (const float*)d_in[2];
  const float* Wk = (const float*)d_in[3];
  const float* Wv = (const float*)d_in[4];
  const float* Wp = (const float*)d_in[5];
  const float* Wg = (const float*)d_in[6];
  const float* cs = (const float*)d_in[7];
  const float* sn = (const float*)d_in[8];
  const int*   wl = (const int*)d_in[9];
  float* out = (float*)d_out;

  const int C = N_HEAD * HEAD_DIM;       // 2048
  const int T = in_sizes[7] / (HEAD_DIM / 2);
  const int B = in_sizes[0] / (T * C);
  const int M = B * T;

  bf16* xb   = (bf16*)d_ws;                    // [M][C]
  bf16* wqkv = xb   + (size_t)M * C;           // [3C][C] (Wq|Wk|Wv rows)
  bf16* wpb  = wqkv + (size_t)3 * C * C;       // [C][C]
  bf16* qkv  = wpb  + (size_t)C * C;           // [M][3C]
  bf16* ybuf = qkv  + (size_t)3 * M * C;       // [M][C]
  bf16* vTb  = xb;  // xb dead after QKV GEMM; reuse for V^T [B][H][128][T]

  const int nx4 = M * C / 4, nw4 = C * C / 4;
  cvt_all<<<dim3((nx4 + 255) / 256, 1, 5), 256, 0, stream>>>(
      x, Wq, Wk, Wv, Wp, xb, wqkv, wpb, nx4, nw4);

  // QKV split for exact-round grids (256 CUs, 1 block/CU):
  // part 1: Q|K cols 0..4095  -> gemm256, (4096/256)*16 = 256 blocks
  // part 2: V  cols 4096..6143 -> gemm128, (4096/128)*8 = 256 blocks
  gemm256<<<dim3((M / 256) * 16), 512, 0, stream>>>(xb, wqkv, qkv, M, 3 * C, C);
  gemm128<bf16><<<dim3((M / 128) * 8), 512, 0, stream>>>(
      xb, wqkv, qkv, M, 3 * C, C, 2 * C);

  rope_rms<<<dim3(M * 2), 256, 0, stream>>>(qkv, cs, sn, T);
  gate_transpose<<<dim3(T / 64, C / 64, B), 256, 0, stream>>>(qkv, x, ve, Wg, vTb, T);
  attn<<<dim3(B * N_HEAD * (T / 128)), 512, 0, stream>>>(qkv, vTb, ybuf, wl, T, B);

  // projection: [M,2048] = ybuf * wpb^T -> gemm128<float>, 32*8 = 256 blocks
  gemm128<float><<<dim3((M / 128) * (C / 256)), 512, 0, stream>>>(
      ybuf, wpb, out, M, C, C, 0);
}